// Round 2
// baseline (1214.164 us; speedup 1.0000x reference)
//
#include <hip/hip_runtime.h>
#include <math.h>

// Router: logits = x[32768,4096] @ w[64,4096]^T (fp32), softmax->top2->renorm.
// Softmax denominator cancels: w1 = 1/(1+exp(l2-l1)), w2 = 1-w1.
//
// d_out layout (all float32):
//   [0      , 65536 ) : indices [8,4096,2] as float
//   [65536  , 131072) : weights [8,4096,2]
//   [131072 , end   ) : logits  [8,4096,64]
//
// Two-pass for index exactness vs fp64 reference:
//   pass1: fp32 GEMM + top-2 + per-row ambiguity flag (gap < DELTA) in d_ws
//   pass2: flagged rows only — fp64 recompute of top-4 candidate dots,
//          exact ordering, overwrite indices+weights.

#define B_ROWS 64
#define KT     64
#define XS     68   // pad 64->68: 16B-aligned rows
#define LS     68
#define DELTA  1e-3f

__global__ __launch_bounds__(256, 2)
void router_pass1(const float* __restrict__ x,
                  const float* __restrict__ w,
                  float* __restrict__ out,
                  int* __restrict__ flags)
{
    __shared__ float x_lds[B_ROWS * XS];
    __shared__ float l_lds[B_ROWS * LS];

    const int tid  = threadIdx.x;
    const int lane = tid & 63;
    const int row0 = blockIdx.x * B_ROWS;
    const int e0 = __builtin_amdgcn_readfirstlane((tid >> 6) << 4);

    float acc[16];
#pragma unroll
    for (int i = 0; i < 16; ++i) acc[i] = 0.0f;

    for (int k0 = 0; k0 < 4096; k0 += KT) {
        __syncthreads();
#pragma unroll
        for (int j = 0; j < 4; ++j) {
            const int f = j * 1024 + tid * 4;
            const int r = f >> 6;
            const int k = f & 63;
            const float4 v = *(const float4*)(x + (size_t)(row0 + r) * 4096 + k0 + k);
            *(float4*)(&x_lds[r * XS + k]) = v;
        }
        __syncthreads();

        for (int kk = 0; kk < KT; kk += 4) {
            const float4 xr = *(const float4*)(&x_lds[lane * XS + kk]);
#pragma unroll
            for (int e = 0; e < 16; ++e) {
                const float4 wv = *(const float4*)(w + (size_t)(e0 + e) * 4096 + k0 + kk);
                acc[e] = fmaf(xr.x, wv.x, acc[e]);
                acc[e] = fmaf(xr.y, wv.y, acc[e]);
                acc[e] = fmaf(xr.z, wv.z, acc[e]);
                acc[e] = fmaf(xr.w, wv.w, acc[e]);
            }
        }
    }

    __syncthreads();
#pragma unroll
    for (int q = 0; q < 4; ++q) {
        float4 v;
        v.x = acc[4 * q + 0];
        v.y = acc[4 * q + 1];
        v.z = acc[4 * q + 2];
        v.w = acc[4 * q + 3];
        *(float4*)(&l_lds[lane * LS + e0 + 4 * q]) = v;
    }
    __syncthreads();

    {
        float* lg = out + 131072 + (size_t)row0 * 64;
#pragma unroll
        for (int j = 0; j < 4; ++j) {
            const int f = j * 1024 + tid * 4;
            const int r = f >> 6;
            const int e = f & 63;
            const float4 v = *(const float4*)(&l_lds[r * LS + e]);
            *(float4*)(lg + f) = v;
        }
    }

    if (tid < 64) {
        const int r = tid;
        float b1 = -3.4e38f, b2 = -3.4e38f, b3 = -3.4e38f;
        int i1 = 0, i2 = 0;
        for (int eq = 0; eq < 16; ++eq) {
            const float4 v4 = *(const float4*)(&l_lds[r * LS + eq * 4]);
            const float vv[4] = {v4.x, v4.y, v4.z, v4.w};
#pragma unroll
            for (int j = 0; j < 4; ++j) {
                const float v = vv[j];
                const int   e = eq * 4 + j;
                if (v > b1)      { b3 = b2; b2 = b1; i2 = i1; b1 = v; i1 = e; }
                else if (v > b2) { b3 = b2; b2 = v; i2 = e; }
                else if (v > b3) { b3 = v; }
            }
        }
        const float g   = __expf(b2 - b1);
        const float inv = 1.0f / (1.0f + g);
        const size_t o  = (size_t)(row0 + r) * 2;
        out[o]     = (float)i1;
        out[o + 1] = (float)i2;
        out[65536 + o]     = inv;
        out[65536 + o + 1] = g * inv;
        flags[row0 + r] = ((b1 - b2 < DELTA) || (b2 - b3 < DELTA)) ? 1 : 0;
    }
}

// One wave per (possibly) flagged row; early-out when flag==0.
__global__ __launch_bounds__(256, 2)
void router_pass2(const float* __restrict__ x,
                  const float* __restrict__ w,
                  float* __restrict__ out,
                  const int* __restrict__ flags)
{
    const int wv   = threadIdx.x >> 6;
    const int lane = threadIdx.x & 63;
    const int base = blockIdx.x * 64 + wv * 16;

    for (int r = 0; r < 16; ++r) {
        const int row = base + r;
        if (!flags[row]) continue;   // wave-uniform

        const float* lg = out + 131072 + (size_t)row * 64;
        const float my = lg[lane];
        float wval = my;

        int ec[4];
#pragma unroll
        for (int m = 0; m < 4; ++m) {
            float v = wval;
            int   id = lane;
            // argmax with lowest-index tie-break
            for (int off = 32; off; off >>= 1) {
                const float ov = __shfl_xor(v, off);
                const int   oi = __shfl_xor(id, off);
                if (ov > v || (ov == v && oi < id)) { v = ov; id = oi; }
            }
            ec[m] = id;                 // uniform across lanes
            if (lane == id) wval = -3.4e38f;
        }

        double s0 = 0.0, s1 = 0.0, s2 = 0.0, s3 = 0.0;
        const float* xr = x + (size_t)row * 4096;
        const float* w0 = w + (size_t)ec[0] * 4096;
        const float* w1 = w + (size_t)ec[1] * 4096;
        const float* w2 = w + (size_t)ec[2] * 4096;
        const float* w3 = w + (size_t)ec[3] * 4096;
        for (int k = lane; k < 4096; k += 64) {
            const double xd = (double)xr[k];
            s0 += xd * (double)w0[k];
            s1 += xd * (double)w1[k];
            s2 += xd * (double)w2[k];
            s3 += xd * (double)w3[k];
        }
        for (int off = 32; off; off >>= 1) {
            s0 += __shfl_xor(s0, off);
            s1 += __shfl_xor(s1, off);
            s2 += __shfl_xor(s2, off);
            s3 += __shfl_xor(s3, off);
        }

        if (lane == 0) {
            double v4[4] = { s0, s1, s2, s3 };
            int    id[4] = { ec[0], ec[1], ec[2], ec[3] };
#pragma unroll
            for (int a = 0; a < 3; ++a)
#pragma unroll
                for (int b = a + 1; b < 4; ++b)
                    if (v4[b] > v4[a] || (v4[b] == v4[a] && id[b] < id[a])) {
                        double tv = v4[a]; v4[a] = v4[b]; v4[b] = tv;
                        int    ti = id[a]; id[a] = id[b]; id[b] = ti;
                    }
            const double g   = exp(v4[1] - v4[0]);
            const double inv = 1.0 / (1.0 + g);
            const size_t o   = (size_t)row * 2;
            out[o]     = (float)id[0];
            out[o + 1] = (float)id[1];
            out[65536 + o]     = (float)inv;
            out[65536 + o + 1] = (float)(g * inv);
        }
    }
}

extern "C" void kernel_launch(void* const* d_in, const int* in_sizes, int n_in,
                              void* d_out, int out_size, void* d_ws, size_t ws_size,
                              hipStream_t stream) {
    const float* x = (const float*)d_in[0];   // [8,4096,4096]
    const float* w = (const float*)d_in[1];   // [64,4096]
    float* out = (float*)d_out;
    int* flags = (int*)d_ws;                  // 32768 ints = 128 KB

    hipLaunchKernelGGL(router_pass1, dim3(512), dim3(256), 0, stream, x, w, out, flags);
    hipLaunchKernelGGL(router_pass2, dim3(512), dim3(256), 0, stream, x, w, out, flags);
}